// Round 3
// baseline (508.354 us; speedup 1.0000x reference)
//
#include <hip/hip_runtime.h>
#include <stdint.h>

#define B_ 512
#define D_ 512
#define C_ 100000
#define CK_ 300000
#define S_ 30.0f
#define COSM_ 0.8775825618903728f
#define SINM_ 0.4794255386042030f
#define TH_ (-0.8775825618903728f)
#define MM_ 0.2397127693021015f
#define EPS_ 1e-12f

#define BM 128
#define BN 96
#define BK 64

typedef float f32x4 __attribute__((ext_vector_type(4)));
typedef short s16x8 __attribute__((ext_vector_type(8)));
typedef unsigned long long u64;
typedef unsigned int u32;

__device__ __forceinline__ unsigned short f2bf(float f){
  u32 u = __float_as_uint(f);
  u += 0x7FFFu + ((u >> 16) & 1u);   // round-to-nearest-even
  return (unsigned short)(u >> 16);
}

// ---------------- normalize x rows -> bf16 ----------------
__global__ void k_normx(const float* __restrict__ x, unsigned short* __restrict__ xn){
  int row  = blockIdx.x * 4 + (threadIdx.x >> 6);
  int lane = threadIdx.x & 63;
  const float* xr = x + (size_t)row * D_ + lane * 8;
  float4 v0 = *(const float4*)xr;
  float4 v1 = *(const float4*)(xr + 4);
  float s = v0.x*v0.x + v0.y*v0.y + v0.z*v0.z + v0.w*v0.w
          + v1.x*v1.x + v1.y*v1.y + v1.z*v1.z + v1.w*v1.w;
  #pragma unroll
  for (int off = 1; off < 64; off <<= 1) s += __shfl_xor(s, off);
  float inv = 1.f / fmaxf(sqrtf(s), EPS_);
  s16x8 h;
  h[0] = (short)f2bf(v0.x*inv); h[1] = (short)f2bf(v0.y*inv);
  h[2] = (short)f2bf(v0.z*inv); h[3] = (short)f2bf(v0.w*inv);
  h[4] = (short)f2bf(v1.x*inv); h[5] = (short)f2bf(v1.y*inv);
  h[6] = (short)f2bf(v1.z*inv); h[7] = (short)f2bf(v1.w*inv);
  *(s16x8*)(xn + (size_t)row * D_ + lane * 8) = h;
}

// ---------------- zero the per-row reduction buffers ----------------
__global__ void k_init(float* __restrict__ sumexp, u64* __restrict__ packed,
                       float* __restrict__ phi){
  int i = threadIdx.x;
  sumexp[i] = 0.f;
  packed[i] = 0ull;
  phi[i]    = 0.f;
}

// ---------------- fused GEMM + norm + subcenter-max + lse/argmax ----------------
__global__ __launch_bounds__(256, 3) void k_gemm(
    const unsigned short* __restrict__ xn, const float* __restrict__ w,
    const int* __restrict__ label,
    float* __restrict__ sumexp_g, u64* __restrict__ packed_g,
    float* __restrict__ phi_g)
{
  // m214-verified geometry: 128-byte LDS rows, byte ^= (row&7)<<4 on write AND read
  __shared__ union {
    struct { unsigned short a[BM*BK]; unsigned short b[BN*BK]; } st; // 16384+12288 B
    float mx[BM*33];                                                 // 16896 B
  } sm;
  __shared__ float invs[BN];
  __shared__ int   slab[BM];

  // bijective XCD-chunked mapping (12500 blocks, 8 XCDs: q=1562, r=4).
  const int bid = blockIdx.x;
  const int xcd = bid & 7;
  const int i8  = bid >> 3;
  const int seq = (xcd < 4) ? (xcd*1563 + i8) : (6252 + (xcd-4)*1562 + i8);
  const int ct = seq >> 2;                 // column tile 0..3124
  const int rt = seq & 3;                  // row tile 0..3
  const int rowbase = rt * BM;
  const int colbase = ct * BN;

  const int tid  = threadIdx.x;
  const int lane = tid & 63;
  const int wid  = tid >> 6;
  const int wm   = wid >> 1, wn = wid & 1; // 2x2 wave grid, wave tile 64x48
  const int lc15 = lane & 15, lhi = lane >> 4;

  if (tid < BM) slab[tid] = label[rowbase + tid];

  // ---- A staging: 4 passes x 256 thr x 16B. row = p*32 + (tid>>3), u = tid&7 ----
  const int arow0 = tid >> 3, au = tid & 7;
  const unsigned short* asrc0 = xn + (size_t)(rowbase + arow0) * D_ + au * 8;
  const int adst0 = arow0 * BK + ((au * 8) ^ ((arow0 & 7) << 3));   // ushort units; <<3 us = <<4 bytes

  // ---- B staging: 6 passes x 256 thr x (16B fp32 -> 8B bf16) ----
  // pos = p*16 + c, c = tid>>4 (class), j = p%3 (subcenter), wnp = p/3
  const int bc = tid >> 4, bu = tid & 15;
  const float* bsrc0 = w + (size_t)(colbase + bc * 3) * D_ + bu * 4;
  const int bdst0 = bc * BK + ((bu * 4) ^ ((bc & 7) << 3));

  // ---- fragment read offsets (same swizzle) ----
  const int swz = (lc15 & 7) << 3;
  int aoff[4][2], boff[3][2];
  #pragma unroll
  for (int m = 0; m < 4; ++m){
    int row = wm*64 + m*16 + lc15;
    #pragma unroll
    for (int ks = 0; ks < 2; ++ks)
      aoff[m][ks] = row * BK + ((ks*32 + lhi*8) ^ swz);
  }
  #pragma unroll
  for (int n = 0; n < 3; ++n){
    int row = wn*48 + n*16 + lc15;
    #pragma unroll
    for (int ks = 0; ks < 2; ++ks)
      boff[n][ks] = row * BK + ((ks*32 + lhi*8) ^ swz);
  }

  f32x4 acc[4][3] = {};
  float sq[6] = {0.f,0.f,0.f,0.f,0.f,0.f};

  for (int kt = 0; kt < D_/BK; ++kt){      // 8 iterations
    const int k0 = kt * BK;
    #pragma unroll
    for (int p = 0; p < 4; ++p){
      s16x8 v = *(const s16x8*)(asrc0 + (size_t)p*32*D_ + k0);
      *(s16x8*)(&sm.st.a[adst0 + p*32*BK]) = v;
    }
    #pragma unroll
    for (int p = 0; p < 6; ++p){
      float4 v = *(const float4*)(bsrc0 + (size_t)((p/3)*48 + (p%3)) * D_ + k0);
      sq[p] += v.x*v.x + v.y*v.y + v.z*v.z + v.w*v.w;
      ushort4 h;
      h.x = f2bf(v.x); h.y = f2bf(v.y); h.z = f2bf(v.z); h.w = f2bf(v.w);
      *(ushort4*)(&sm.st.b[bdst0 + p*16*BK]) = h;
    }
    __syncthreads();
    #pragma unroll
    for (int ks = 0; ks < 2; ++ks){
      s16x8 af[4], bfr[3];
      #pragma unroll
      for (int m = 0; m < 4; ++m) af[m]  = *(const s16x8*)(&sm.st.a[aoff[m][ks]]);
      #pragma unroll
      for (int n = 0; n < 3; ++n) bfr[n] = *(const s16x8*)(&sm.st.b[boff[n][ks]]);
      #pragma unroll
      for (int m = 0; m < 4; ++m)
        #pragma unroll
        for (int n = 0; n < 3; ++n)
          acc[m][n] = __builtin_amdgcn_mfma_f32_16x16x32_bf16(af[m], bfr[n], acc[m][n], 0, 0, 0);
    }
    __syncthreads();
  }

  // weight-row inverse norms: row p*16 + (tid>>4), sumsq spread over 16 adjacent threads
  #pragma unroll
  for (int p = 0; p < 6; ++p){
    float s = sq[p];
    s += __shfl_xor(s, 1); s += __shfl_xor(s, 2);
    s += __shfl_xor(s, 4); s += __shfl_xor(s, 8);
    if ((tid & 15) == 0) invs[p*16 + (tid >> 4)] = 1.f / fmaxf(sqrtf(s), EPS_);
  }
  __syncthreads();

  // in-register subcenter max (3 n-frags = 3 subcenters of the SAME class), phi at label, write mx
  {
    float inv0 = invs[wn*48 +  0 + lc15];
    float inv1 = invs[wn*48 + 16 + lc15];
    float inv2 = invs[wn*48 + 32 + lc15];
    int cls    = wn*16 + lc15;            // local class 0..31
    int lcbase = ct * 32;
    #pragma unroll
    for (int m = 0; m < 4; ++m){
      #pragma unroll
      for (int r = 0; r < 4; ++r){
        int rl = wm*64 + m*16 + lhi*4 + r;
        float v = fmaxf(fmaxf(acc[m][0][r]*inv0, acc[m][1][r]*inv1), acc[m][2][r]*inv2);
        if (slab[rl] - lcbase == cls){
          float cy = v;
          float s2 = fminf(fmaxf(1.f - cy*cy, 0.f), 1.f);
          float sy = sqrtf(s2);
          float ph = cy*COSM_ - sy*SINM_;
          if (!(cy - TH_ > 0.f)) ph = cy - MM_;
          phi_g[rowbase + rl] = ph;       // unique writer
          v = ph;
        }
        sm.mx[rl*33 + cls] = v;
      }
    }
  }
  __syncthreads();

  // per-row reduction over the 32 classes: 2 threads per row
  {
    int row  = tid >> 1;
    int half = tid & 1;
    int grow = rowbase + row;
    float se = 0.f;
    u64 pk = 0ull;
    #pragma unroll
    for (int c = 0; c < 16; ++c){
      int lc = half*16 + c;
      float v = sm.mx[row*33 + lc];
      se += __expf(S_*v - S_);            // shift by 30 (= S*max possible cos)
      u32 u = __float_as_uint(v);
      u = (v >= 0.f) ? (u | 0x80000000u) : ~u;            // sortable float
      u64 p = ((u64)u << 32) | (u32)~(u32)(ct*32 + lc);   // ~idx: first-occurrence ties
      pk = (p > pk) ? p : pk;
    }
    se += __shfl_xor(se, 1);
    u32 lo = (u32)pk, hi = (u32)(pk >> 32);
    u32 plo = __shfl_xor(lo, 1), phi2 = __shfl_xor(hi, 1);
    u64 po = ((u64)phi2 << 32) | plo;
    pk = (po > pk) ? po : pk;
    if (half == 0){
      atomicAdd(&sumexp_g[grow], se);
      atomicMax(&packed_g[grow], pk);
    }
  }
}

// ---------------- finalize: loss + prec1 ----------------
__global__ void k_final(const float* __restrict__ sumexp, const u64* __restrict__ packed,
                        const float* __restrict__ phi, const int* __restrict__ label,
                        float* __restrict__ out){
  int i = threadIdx.x;  // 512 threads, one row each
  float lse  = S_ + logf(sumexp[i]);
  float loss = lse - S_ * phi[i];
  u32 pred = ~(u32)(packed[i] & 0xFFFFFFFFull);
  float corr = (pred == (u32)label[i]) ? 1.f : 0.f;
  float a = loss, b = corr;
  #pragma unroll
  for (int off = 1; off < 64; off <<= 1){ a += __shfl_xor(a, off); b += __shfl_xor(b, off); }
  __shared__ float sa[8], sb[8];
  if ((i & 63) == 0){ sa[i >> 6] = a; sb[i >> 6] = b; }
  __syncthreads();
  if (i == 0){
    float ta = 0.f, tb = 0.f;
    #pragma unroll
    for (int j = 0; j < 8; ++j){ ta += sa[j]; tb += sb[j]; }
    out[0] = ta / 512.f;
    out[1] = tb * (100.f / 512.f);
  }
}

extern "C" void kernel_launch(void* const* d_in, const int* in_sizes, int n_in,
                              void* d_out, int out_size, void* d_ws, size_t ws_size,
                              hipStream_t stream){
  const float* x     = (const float*)d_in[0];
  const int*   label = (const int*)d_in[1];
  const float* w     = (const float*)d_in[2];
  float* out = (float*)d_out;
  char* ws = (char*)d_ws;

  unsigned short* xn = (unsigned short*)ws;            // 512*512*2 = 524288 B
  float* sumexp = (float*)(ws + 524288);               // 2048 B
  u64*   packed = (u64*)(ws + 524288 + 2048);          // 4096 B
  float* phi    = (float*)(ws + 524288 + 2048 + 4096); // 2048 B

  k_init <<<1,   512, 0, stream>>>(sumexp, packed, phi);
  k_normx<<<128, 256, 0, stream>>>(x, xn);
  k_gemm <<<(CK_/BN)*4, 256, 0, stream>>>(xn, w, label, sumexp, packed, phi);
  k_final<<<1,   512, 0, stream>>>(sumexp, packed, phi, label, out);
}

// Round 4
// 506.444 us; speedup vs baseline: 1.0038x; 1.0038x over previous
//
#include <hip/hip_runtime.h>
#include <stdint.h>

#define B_ 512
#define D_ 512
#define C_ 100000
#define CK_ 300000
#define S_ 30.0f
#define COSM_ 0.8775825618903728f
#define SINM_ 0.4794255386042030f
#define TH_ (-0.8775825618903728f)
#define MM_ 0.2397127693021015f
#define EPS_ 1e-12f

#define BM 128
#define BN 96
#define BK 64

typedef float f32x4 __attribute__((ext_vector_type(4)));
typedef short s16x8 __attribute__((ext_vector_type(8)));
typedef unsigned long long u64;
typedef unsigned int u32;

#define GLL16(g, l) __builtin_amdgcn_global_load_lds( \
    (const __attribute__((address_space(1))) void*)(g), \
    (__attribute__((address_space(3))) void*)(l), 16, 0, 0)

__device__ __forceinline__ unsigned short f2bf(float f){
  u32 u = __float_as_uint(f);
  u += 0x7FFFu + ((u >> 16) & 1u);   // round-to-nearest-even
  return (unsigned short)(u >> 16);
}

// ---------------- normalize rows of [nrows, 512] fp32 -> unit bf16 ----------------
__global__ void k_norm(const float* __restrict__ src, unsigned short* __restrict__ dst){
  int row  = blockIdx.x * 4 + (threadIdx.x >> 6);
  int lane = threadIdx.x & 63;
  const float* r = src + (size_t)row * D_ + lane * 8;
  float4 v0 = *(const float4*)r;
  float4 v1 = *(const float4*)(r + 4);
  float s = v0.x*v0.x + v0.y*v0.y + v0.z*v0.z + v0.w*v0.w
          + v1.x*v1.x + v1.y*v1.y + v1.z*v1.z + v1.w*v1.w;
  #pragma unroll
  for (int off = 1; off < 64; off <<= 1) s += __shfl_xor(s, off);
  float inv = 1.f / fmaxf(sqrtf(s), EPS_);
  s16x8 h;
  h[0] = (short)f2bf(v0.x*inv); h[1] = (short)f2bf(v0.y*inv);
  h[2] = (short)f2bf(v0.z*inv); h[3] = (short)f2bf(v0.w*inv);
  h[4] = (short)f2bf(v1.x*inv); h[5] = (short)f2bf(v1.y*inv);
  h[6] = (short)f2bf(v1.z*inv); h[7] = (short)f2bf(v1.w*inv);
  *(s16x8*)(dst + (size_t)row * D_ + lane * 8) = h;
}

// ---------------- zero the per-row reduction buffers ----------------
__global__ void k_init(float* __restrict__ sumexp, u64* __restrict__ packed,
                       float* __restrict__ phi){
  int i = threadIdx.x;
  sumexp[i] = 0.f;
  packed[i] = 0ull;
  phi[i]    = 0.f;
}

// ================= PATH A: bf16 GEMM with global_load_lds staging =================
__global__ __launch_bounds__(256, 4) void k_gemm2(
    const unsigned short* __restrict__ xn, const unsigned short* __restrict__ wnb,
    const int* __restrict__ label,
    float* __restrict__ sumexp_g, u64* __restrict__ packed_g,
    float* __restrict__ phi_g)
{
  __shared__ union {
    unsigned short st[BM*BK + BN*BK];   // A tile then B tile, linear 128B rows
    float mx[BM*33];
  } sm;
  __shared__ int slab[BM];

  // bijective XCD-chunked mapping (12500 blocks, 8 XCDs: q=1562, r=4)
  const int bid = blockIdx.x;
  const int xcd = bid & 7;
  const int i8  = bid >> 3;
  const int seq = (xcd < 4) ? (xcd*1563 + i8) : (6252 + (xcd-4)*1562 + i8);
  const int ct = seq >> 2;                 // column tile 0..3124
  const int rt = seq & 3;                  // row tile 0..3
  const int rowbase = rt * BM;
  const int colbase = ct * BN;

  const int tid  = threadIdx.x;
  const int lane = tid & 63;
  const int wid  = tid >> 6;
  const int wm   = wid >> 1, wn = wid & 1; // 2x2 wave grid, wave tile 64x48
  const int lc15 = lane & 15, lhi = lane >> 4;

  if (tid < BM) slab[tid] = label[rowbase + tid];

  // ---- staging addresses (kt-invariant). LDS is LINEAR; the XOR swizzle is
  // applied on the per-lane GLOBAL source and again on the ds_read (rule #21).
  const int arow = tid >> 3, aslot = tid & 7;   // 32 rows/pass, 8 x 16B slots/row
  const unsigned short* asrc[4]; unsigned short* adst[4];
  #pragma unroll
  for (int p = 0; p < 4; ++p){
    int row = p*32 + arow;
    asrc[p] = xn + (size_t)(rowbase + row) * D_ + ((aslot ^ (row & 7)) * 8);
    adst[p] = &sm.st[row*BK + aslot*8];
  }
  const unsigned short* bsrc[3]; unsigned short* bdst[3];
  #pragma unroll
  for (int p = 0; p < 3; ++p){
    int pos = p*32 + arow;                 // permuted tile position 0..95
    int wnp = pos / 48, rem = pos % 48;
    int j = rem >> 4, c = rem & 15;        // subcenter j of class (wnp*16+c)
    int wrow = colbase + (wnp*16 + c)*3 + j;
    bsrc[p] = wnb + (size_t)wrow * D_ + ((aslot ^ (pos & 7)) * 8);
    bdst[p] = &sm.st[BM*BK + pos*BK + aslot*8];
  }

  // ---- fragment read offsets (ushort units), same involution on read ----
  const int s7 = lc15 & 7;
  int aoff[4][2], boff[3][2];
  #pragma unroll
  for (int m = 0; m < 4; ++m){
    int row = wm*64 + m*16 + lc15;
    #pragma unroll
    for (int ks = 0; ks < 2; ++ks)
      aoff[m][ks] = row*BK + (((ks*4 + lhi) ^ s7) << 3);
  }
  #pragma unroll
  for (int n = 0; n < 3; ++n){
    int pos = wn*48 + n*16 + lc15;
    #pragma unroll
    for (int ks = 0; ks < 2; ++ks)
      boff[n][ks] = BM*BK + pos*BK + (((ks*4 + lhi) ^ s7) << 3);
  }

  f32x4 acc[4][3] = {};

  for (int kt = 0; kt < D_/BK; ++kt){      // 8 iterations
    const int k0 = kt * BK;
    #pragma unroll
    for (int p = 0; p < 4; ++p) GLL16(asrc[p] + k0, adst[p]);
    #pragma unroll
    for (int p = 0; p < 3; ++p) GLL16(bsrc[p] + k0, bdst[p]);
    __syncthreads();                       // drains vmcnt (gl_lds) + orders LDS
    #pragma unroll
    for (int ks = 0; ks < 2; ++ks){
      s16x8 af[4], bfr[3];
      #pragma unroll
      for (int m = 0; m < 4; ++m) af[m]  = *(const s16x8*)(&sm.st[aoff[m][ks]]);
      #pragma unroll
      for (int n = 0; n < 3; ++n) bfr[n] = *(const s16x8*)(&sm.st[boff[n][ks]]);
      #pragma unroll
      for (int m = 0; m < 4; ++m)
        #pragma unroll
        for (int n = 0; n < 3; ++n)
          acc[m][n] = __builtin_amdgcn_mfma_f32_16x16x32_bf16(af[m], bfr[n], acc[m][n], 0, 0, 0);
    }
    __syncthreads();
  }

  // acc IS cosine (both operands unit-norm). Subcenter max in-register:
  // the 3 n-fragments are the 3 subcenters of class (wn*16 + lc15).
  {
    int cls    = wn*16 + lc15;
    int lcbase = ct * 32;
    #pragma unroll
    for (int m = 0; m < 4; ++m){
      #pragma unroll
      for (int r = 0; r < 4; ++r){
        int rl = wm*64 + m*16 + lhi*4 + r;
        float v = fmaxf(fmaxf(acc[m][0][r], acc[m][1][r]), acc[m][2][r]);
        if (slab[rl] - lcbase == cls){
          float cy = v;
          float s2 = fminf(fmaxf(1.f - cy*cy, 0.f), 1.f);
          float sy = sqrtf(s2);
          float ph = cy*COSM_ - sy*SINM_;
          if (!(cy - TH_ > 0.f)) ph = cy - MM_;
          phi_g[rowbase + rl] = ph;        // unique writer
          v = ph;
        }
        sm.mx[rl*33 + cls] = v;
      }
    }
  }
  __syncthreads();

  // per-row LSE + argmax over this block's 32 classes: 2 threads per row
  {
    int row  = tid >> 1;
    int half = tid & 1;
    int grow = rowbase + row;
    float se = 0.f;
    u64 pk = 0ull;
    #pragma unroll
    for (int c = 0; c < 16; ++c){
      int lc = half*16 + c;
      float v = sm.mx[row*33 + lc];
      se += __expf(S_*v - S_);
      u32 u = __float_as_uint(v);
      u = (v >= 0.f) ? (u | 0x80000000u) : ~u;            // sortable float
      u64 p = ((u64)u << 32) | (u32)~(u32)(ct*32 + lc);   // ~idx: first-occurrence ties
      pk = (p > pk) ? p : pk;
    }
    se += __shfl_xor(se, 1);
    u32 lo = (u32)pk, hi = (u32)(pk >> 32);
    u32 plo = __shfl_xor(lo, 1), phi2 = __shfl_xor(hi, 1);
    u64 po = ((u64)phi2 << 32) | plo;
    pk = (po > pk) ? po : pk;
    if (half == 0){
      atomicAdd(&sumexp_g[grow], se);
      atomicMax(&packed_g[grow], pk);
    }
  }
}

// ================= PATH B (fallback, ws too small): round-3 fused kernel =========
__global__ __launch_bounds__(256, 3) void k_gemm_fused(
    const unsigned short* __restrict__ xn, const float* __restrict__ w,
    const int* __restrict__ label,
    float* __restrict__ sumexp_g, u64* __restrict__ packed_g,
    float* __restrict__ phi_g)
{
  __shared__ union {
    struct { unsigned short a[BM*BK]; unsigned short b[BN*BK]; } st;
    float mx[BM*33];
  } sm;
  __shared__ float invs[BN];
  __shared__ int   slab[BM];

  const int bid = blockIdx.x;
  const int xcd = bid & 7;
  const int i8  = bid >> 3;
  const int seq = (xcd < 4) ? (xcd*1563 + i8) : (6252 + (xcd-4)*1562 + i8);
  const int ct = seq >> 2;
  const int rt = seq & 3;
  const int rowbase = rt * BM;
  const int colbase = ct * BN;

  const int tid  = threadIdx.x;
  const int lane = tid & 63;
  const int wid  = tid >> 6;
  const int wm   = wid >> 1, wn = wid & 1;
  const int lc15 = lane & 15, lhi = lane >> 4;

  if (tid < BM) slab[tid] = label[rowbase + tid];

  const int arow0 = tid >> 3, au = tid & 7;
  const unsigned short* asrc0 = xn + (size_t)(rowbase + arow0) * D_ + au * 8;
  const int adst0 = arow0 * BK + ((au * 8) ^ ((arow0 & 7) << 3));

  const int bc = tid >> 4, bu = tid & 15;
  const float* bsrc0 = w + (size_t)(colbase + bc * 3) * D_ + bu * 4;
  const int bdst0 = bc * BK + ((bu * 4) ^ ((bc & 7) << 3));

  const int swz = (lc15 & 7) << 3;
  int aoff[4][2], boff[3][2];
  #pragma unroll
  for (int m = 0; m < 4; ++m){
    int row = wm*64 + m*16 + lc15;
    #pragma unroll
    for (int ks = 0; ks < 2; ++ks) aoff[m][ks] = row * BK + ((ks*32 + lhi*8) ^ swz);
  }
  #pragma unroll
  for (int n = 0; n < 3; ++n){
    int row = wn*48 + n*16 + lc15;
    #pragma unroll
    for (int ks = 0; ks < 2; ++ks) boff[n][ks] = row * BK + ((ks*32 + lhi*8) ^ swz);
  }

  f32x4 acc[4][3] = {};
  float sq[6] = {0.f,0.f,0.f,0.f,0.f,0.f};

  for (int kt = 0; kt < D_/BK; ++kt){
    const int k0 = kt * BK;
    #pragma unroll
    for (int p = 0; p < 4; ++p){
      s16x8 v = *(const s16x8*)(asrc0 + (size_t)p*32*D_ + k0);
      *(s16x8*)(&sm.st.a[adst0 + p*32*BK]) = v;
    }
    #pragma unroll
    for (int p = 0; p < 6; ++p){
      float4 v = *(const float4*)(bsrc0 + (size_t)((p/3)*48 + (p%3)) * D_ + k0);
      sq[p] += v.x*v.x + v.y*v.y + v.z*v.z + v.w*v.w;
      ushort4 h;
      h.x = f2bf(v.x); h.y = f2bf(v.y); h.z = f2bf(v.z); h.w = f2bf(v.w);
      *(ushort4*)(&sm.st.b[bdst0 + p*16*BK]) = h;
    }
    __syncthreads();
    #pragma unroll
    for (int ks = 0; ks < 2; ++ks){
      s16x8 af[4], bfr[3];
      #pragma unroll
      for (int m = 0; m < 4; ++m) af[m]  = *(const s16x8*)(&sm.st.a[aoff[m][ks]]);
      #pragma unroll
      for (int n = 0; n < 3; ++n) bfr[n] = *(const s16x8*)(&sm.st.b[boff[n][ks]]);
      #pragma unroll
      for (int m = 0; m < 4; ++m)
        #pragma unroll
        for (int n = 0; n < 3; ++n)
          acc[m][n] = __builtin_amdgcn_mfma_f32_16x16x32_bf16(af[m], bfr[n], acc[m][n], 0, 0, 0);
    }
    __syncthreads();
  }

  #pragma unroll
  for (int p = 0; p < 6; ++p){
    float s = sq[p];
    s += __shfl_xor(s, 1); s += __shfl_xor(s, 2);
    s += __shfl_xor(s, 4); s += __shfl_xor(s, 8);
    if ((tid & 15) == 0) invs[p*16 + (tid >> 4)] = 1.f / fmaxf(sqrtf(s), EPS_);
  }
  __syncthreads();

  {
    float inv0 = invs[wn*48 +  0 + lc15];
    float inv1 = invs[wn*48 + 16 + lc15];
    float inv2 = invs[wn*48 + 32 + lc15];
    int cls    = wn*16 + lc15;
    int lcbase = ct * 32;
    #pragma unroll
    for (int m = 0; m < 4; ++m){
      #pragma unroll
      for (int r = 0; r < 4; ++r){
        int rl = wm*64 + m*16 + lhi*4 + r;
        float v = fmaxf(fmaxf(acc[m][0][r]*inv0, acc[m][1][r]*inv1), acc[m][2][r]*inv2);
        if (slab[rl] - lcbase == cls){
          float cy = v;
          float s2 = fminf(fmaxf(1.f - cy*cy, 0.f), 1.f);
          float sy = sqrtf(s2);
          float ph = cy*COSM_ - sy*SINM_;
          if (!(cy - TH_ > 0.f)) ph = cy - MM_;
          phi_g[rowbase + rl] = ph;
          v = ph;
        }
        sm.mx[rl*33 + cls] = v;
      }
    }
  }
  __syncthreads();

  {
    int row  = tid >> 1;
    int half = tid & 1;
    int grow = rowbase + row;
    float se = 0.f;
    u64 pk = 0ull;
    #pragma unroll
    for (int c = 0; c < 16; ++c){
      int lc = half*16 + c;
      float v = sm.mx[row*33 + lc];
      se += __expf(S_*v - S_);
      u32 u = __float_as_uint(v);
      u = (v >= 0.f) ? (u | 0x80000000u) : ~u;
      u64 p = ((u64)u << 32) | (u32)~(u32)(ct*32 + lc);
      pk = (p > pk) ? p : pk;
    }
    se += __shfl_xor(se, 1);
    u32 lo = (u32)pk, hi = (u32)(pk >> 32);
    u32 plo = __shfl_xor(lo, 1), phi2 = __shfl_xor(hi, 1);
    u64 po = ((u64)phi2 << 32) | plo;
    pk = (po > pk) ? po : pk;
    if (half == 0){
      atomicAdd(&sumexp_g[grow], se);
      atomicMax(&packed_g[grow], pk);
    }
  }
}

// ---------------- finalize: loss + prec1 ----------------
__global__ void k_final(const float* __restrict__ sumexp, const u64* __restrict__ packed,
                        const float* __restrict__ phi, const int* __restrict__ label,
                        float* __restrict__ out){
  int i = threadIdx.x;
  float lse  = S_ + logf(sumexp[i]);
  float loss = lse - S_ * phi[i];
  u32 pred = ~(u32)(packed[i] & 0xFFFFFFFFull);
  float corr = (pred == (u32)label[i]) ? 1.f : 0.f;
  float a = loss, b = corr;
  #pragma unroll
  for (int off = 1; off < 64; off <<= 1){ a += __shfl_xor(a, off); b += __shfl_xor(b, off); }
  __shared__ float sa[8], sb[8];
  if ((i & 63) == 0){ sa[i >> 6] = a; sb[i >> 6] = b; }
  __syncthreads();
  if (i == 0){
    float ta = 0.f, tb = 0.f;
    #pragma unroll
    for (int j = 0; j < 8; ++j){ ta += sa[j]; tb += sb[j]; }
    out[0] = ta / 512.f;
    out[1] = tb * (100.f / 512.f);
  }
}

extern "C" void kernel_launch(void* const* d_in, const int* in_sizes, int n_in,
                              void* d_out, int out_size, void* d_ws, size_t ws_size,
                              hipStream_t stream){
  const float* x     = (const float*)d_in[0];
  const int*   label = (const int*)d_in[1];
  const float* w     = (const float*)d_in[2];
  float* out = (float*)d_out;
  char* ws = (char*)d_ws;

  unsigned short* xn = (unsigned short*)ws;            // 524288 B
  float* sumexp = (float*)(ws + 524288);               // 2048 B
  u64*   packed = (u64*)(ws + 524288 + 2048);          // 4096 B
  float* phi    = (float*)(ws + 524288 + 2048 + 4096); // 2048 B
  unsigned short* wnb = (unsigned short*)(ws + 532480);// 307,200,000 B (Path A)

  const size_t needA = 532480ull + (size_t)CK_ * D_ * 2ull;

  k_init <<<1,   512, 0, stream>>>(sumexp, packed, phi);
  k_norm <<<B_/4, 256, 0, stream>>>(x, xn);
  if (ws_size >= needA){
    k_norm <<<CK_/4, 256, 0, stream>>>(w, wnb);
    k_gemm2<<<(CK_/BN)*4, 256, 0, stream>>>(xn, wnb, label, sumexp, packed, phi);
  } else {
    k_gemm_fused<<<(CK_/BN)*4, 256, 0, stream>>>(xn, w, label, sumexp, packed, phi);
  }
  k_final<<<1,   512, 0, stream>>>(sumexp, packed, phi, label, out);
}